// Round 2
// baseline (1164.101 us; speedup 1.0000x reference)
//
#include <hip/hip_runtime.h>
#include <hip/hip_bf16.h>
#include <cstdint>
#include <cstddef>

// Problem constants
#define B_   2
#define T_   2048
#define DIM_ 4096
#define H_   32
#define HKV_ 8
#define DH_  128
#define MROWS (B_*T_)   // 4096
#define QS_   6144      // row stride of fused QKV activation [4096][6144]
#define KOFF_ 4096      // col offset of K inside QKV
#define VOFF_ 5120      // col offset of V inside QKV

typedef __bf16 bf16_t;
typedef bf16_t bf16x8 __attribute__((ext_vector_type(8)));
typedef bf16_t bf16x4 __attribute__((ext_vector_type(4)));
typedef bf16_t bf16x2 __attribute__((ext_vector_type(2)));
typedef float  f32x4  __attribute__((ext_vector_type(4)));

typedef __attribute__((address_space(1))) void gvoid_t;
typedef __attribute__((address_space(3))) void lvoid_t;

#if __has_builtin(__builtin_amdgcn_exp2f)
#define EXP2F(x) __builtin_amdgcn_exp2f(x)
#else
#define EXP2F(x) exp2f(x)
#endif

__device__ __forceinline__ void gld_lds16(const void* g, void* l) {
  __builtin_amdgcn_global_load_lds((gvoid_t*)g, (lvoid_t*)l, 16, 0, 0);
}

__device__ __forceinline__ f32x4 mfma16(bf16x8 a, bf16x8 b, f32x4 c) {
  return __builtin_amdgcn_mfma_f32_16x16x32_bf16(a, b, c, 0, 0, 0);
}

// ---------------------------------------------------------------------------
// cast fp32 -> bf16 (X)
// ---------------------------------------------------------------------------
__global__ void cast_f32_bf16(const float* __restrict__ in,
                              bf16_t* __restrict__ out, int n4) {
  int i = blockIdx.x * blockDim.x + threadIdx.x;
  if (i < n4) {
    float4 v = ((const float4*)in)[i];
    bf16x4 o;
    o[0] = (bf16_t)v.x; o[1] = (bf16_t)v.y; o[2] = (bf16_t)v.z; o[3] = (bf16_t)v.w;
    ((bf16x4*)out)[i] = o;
  }
}

// ---------------------------------------------------------------------------
// transpose + cast: in fp32 [K][N] -> out bf16 [N][K]
// ---------------------------------------------------------------------------
__global__ void transpose_cast(const float* __restrict__ in,
                               bf16_t* __restrict__ out, int K, int N) {
  __shared__ float tile[32][33];
  int n0 = blockIdx.x * 32, k0 = blockIdx.y * 32;
  int tx = threadIdx.x, ty = threadIdx.y;
#pragma unroll
  for (int j = 0; j < 4; ++j)
    tile[ty + j*8][tx] = in[(size_t)(k0 + ty + j*8) * N + n0 + tx];
  __syncthreads();
#pragma unroll
  for (int j = 0; j < 4; ++j)
    out[(size_t)(n0 + ty + j*8) * K + k0 + tx] = (bf16_t)tile[tx][ty + j*8];
}

// ---------------------------------------------------------------------------
// bf16 MFMA GEMM (m97 structure): C[M][N] = A[M][K] * BT[N][K]^T
// ---------------------------------------------------------------------------
template <int OUT_F32>
__global__ __launch_bounds__(256, 2)
void gemm_bt(const bf16_t* __restrict__ A, const bf16_t* __restrict__ BT,
             void* __restrict__ C, int M, int N, int K) {
  __shared__ __align__(16) bf16_t Als[128 * 32];
  __shared__ __align__(16) bf16_t Bls[128 * 32];
  const int tid  = threadIdx.x;
  const int wave = tid >> 6, lane = tid & 63;
  const int quad = lane >> 4, l16 = lane & 15;
  const int wm = wave >> 1, wn = wave & 1;
  const int m0 = blockIdx.y * 128, n0 = blockIdx.x * 128;

  f32x4 acc[4][4] = {};
  const int srow = lane >> 2;
  const int scol = (lane & 3) * 8;

  for (int k0 = 0; k0 < K; k0 += 32) {
#pragma unroll
    for (int c = 0; c < 2; ++c) {
      int ch = wave * 2 + c;
      gld_lds16(A + (size_t)(m0 + ch*16 + srow) * K + k0 + scol,
                &Als[ch*512 + srow*32 + scol]);
    }
#pragma unroll
    for (int c = 0; c < 2; ++c) {
      int ch = wave * 2 + c;
      gld_lds16(BT + (size_t)(n0 + ch*16 + srow) * K + k0 + scol,
                &Bls[ch*512 + srow*32 + scol]);
    }
    __syncthreads();

    bf16x8 af[4], bfr[4];
#pragma unroll
    for (int mi = 0; mi < 4; ++mi)
      af[mi] = *(const bf16x8*)&Als[(wm*64 + mi*16 + l16)*32 + quad*8];
#pragma unroll
    for (int ni = 0; ni < 4; ++ni)
      bfr[ni] = *(const bf16x8*)&Bls[(wn*64 + ni*16 + l16)*32 + quad*8];
#pragma unroll
    for (int mi = 0; mi < 4; ++mi)
#pragma unroll
      for (int ni = 0; ni < 4; ++ni)
        acc[mi][ni] = mfma16(af[mi], bfr[ni], acc[mi][ni]);
    __syncthreads();
  }

#pragma unroll
  for (int mi = 0; mi < 4; ++mi)
#pragma unroll
    for (int ni = 0; ni < 4; ++ni)
#pragma unroll
      for (int r = 0; r < 4; ++r) {
        int row = m0 + wm*64 + mi*16 + quad*4 + r;
        int col = n0 + wn*64 + ni*16 + l16;
        if (OUT_F32)
          ((float*)C)[(size_t)row * N + col] = acc[mi][ni][r];
        else
          ((bf16_t*)C)[(size_t)row * N + col] = (bf16_t)acc[mi][ni][r];
      }
}

// ---------------------------------------------------------------------------
// in-place RoPE on bf16 rows of stride rowStr at head offset headOff
// ---------------------------------------------------------------------------
__global__ void rope_kernel(bf16_t* __restrict__ X, int Hn, int rowStr,
                            int headOff, int total) {
  int i = blockIdx.x * blockDim.x + threadIdx.x;
  if (i >= total) return;
  int d   = i & 63;
  int rem = i >> 6;
  int h   = rem % Hn; rem /= Hn;
  int t   = rem % T_;
  int b   = rem / T_;
  size_t base = (size_t)(b * T_ + t) * rowStr + headOff + h * DH_;
  float x1 = (float)X[base + d];
  float x2 = (float)X[base + 64 + d];
  float inv_freq = expf(-(float)d * 0.14391156758f);  // theta^(-d/64)
  float ang = (float)t * inv_freq;
  float s, c;
  sincosf(ang, &s, &c);
  X[base + d]      = (bf16_t)(x1 * c - x2 * s);
  X[base + 64 + d] = (bf16_t)(x1 * s + x2 * c);
}

// ---------------------------------------------------------------------------
// V transpose: QKV V-cols [b][t][kv*128+d] (stride QS_) -> VT [b][kv][128][T]
// ---------------------------------------------------------------------------
__global__ void v_transpose(const bf16_t* __restrict__ Vin,
                            bf16_t* __restrict__ VT) {
  __shared__ bf16_t tile[32][33];
  int t0 = blockIdx.x * 32;
  int d0 = blockIdx.y * 32;
  int bk = blockIdx.z;
  int b = bk >> 3, kv = bk & 7;
  int tx = threadIdx.x, ty = threadIdx.y;
#pragma unroll
  for (int j = 0; j < 4; ++j)
    tile[ty + j*8][tx] =
        Vin[(size_t)(b * T_ + t0 + ty + j*8) * QS_ + kv*DH_ + d0 + tx];
  __syncthreads();
#pragma unroll
  for (int j = 0; j < 4; ++j)
    VT[((size_t)bk * DH_ + d0 + ty + j*8) * T_ + t0 + tx] = tile[tx][ty + j*8];
}

// ---------------------------------------------------------------------------
// causal flash attention, transposed-S formulation.
// BQ=128, BKV=64, 256 threads. Flat grid 1024; heavy (large qt) blocks first.
// Each wave: all 64 kv x 32 q. S^T = K Q^T (m=kv, n=q); softmax over kv is
// in-lane + 2 shuffles; P^T -> PV B-operand via 16 packed cross-quad shuffles;
// O^T = V^T P^T.
// ---------------------------------------------------------------------------
__global__ __launch_bounds__(256, 3)
void flash_attn(const bf16_t* __restrict__ QKV, const bf16_t* __restrict__ VT,
                bf16_t* __restrict__ Ob) {
  __shared__ __align__(16) bf16_t Kls[64 * 128];   // [kv][dh], XOR-swizzled 16B chunks
  __shared__ __align__(16) bf16_t Vls[128 * 64];   // [dh][kv], XOR-swizzled

  const int tid = threadIdx.x, wave = tid >> 6, lane = tid & 63;
  const int quad = lane >> 4, l16 = lane & 15;
  const int idx = blockIdx.x;
  const int qt = 15 - (idx & 15);        // reversed: heavy blocks dispatch first
  const int h  = (idx >> 4) & 31;
  const int b  = idx >> 9;
  const int kv = h >> 2;

  const float CSC = 0.12751744642f;      // log2(e)/sqrt(128)

  // Q fragments (B-operand): rows q = qt*128 + wave*32 + qb*16 + l16
  bf16x8 q[2][4];
#pragma unroll
  for (int qb = 0; qb < 2; ++qb) {
    const bf16_t* base =
        QKV + (size_t)(b*T_ + qt*128 + wave*32 + qb*16 + l16) * QS_ + h*DH_;
#pragma unroll
    for (int kk = 0; kk < 4; ++kk)
      q[qb][kk] = *(const bf16x8*)(base + kk*32 + quad*8);
  }

  float m_st[2] = {-3e38f, -3e38f}, l_st[2] = {0.f, 0.f};
  f32x4 o_acc[8][2] = {};

  const int nkv = 2 * (qt + 1);
  for (int kvt = 0; kvt < nkv; ++kvt) {
    __syncthreads();
    // stage K tile [64][128]
    {
      int r_in = lane >> 4, cph = lane & 15;
#pragma unroll
      for (int c = 0; c < 4; ++c) {
        int ch = wave*4 + c, krow = ch*4 + r_in, clog = cph ^ (krow & 7);
        gld_lds16(QKV + (size_t)(b*T_ + kvt*64 + krow) * QS_ + KOFF_ + kv*DH_ + clog*8,
                  &Kls[ch*512 + lane*8]);
      }
      // stage V^T tile [128][64]
      int r8 = lane >> 3, c8 = lane & 7;
#pragma unroll
      for (int c = 0; c < 4; ++c) {
        int ch = wave*4 + c, drow = ch*8 + r8, clog = c8 ^ (drow & 7);
        gld_lds16(VT + ((size_t)(b*HKV_ + kv) * DH_ + drow) * T_ + kvt*64 + clog*8,
                  &Vls[ch*512 + lane*8]);
      }
    }
    __syncthreads();

    // S^T: m=kv (4 blocks), n=q (2 blocks per wave), K=dh=128
    f32x4 s[2][4] = {};   // [qb][nb]
#pragma unroll
    for (int kk = 0; kk < 4; ++kk) {
      bf16x8 kf[4];
#pragma unroll
      for (int nb = 0; nb < 4; ++nb) {
        int krow = nb*16 + l16;
        int pc = (kk*4 + quad) ^ (krow & 7);
        kf[nb] = *(const bf16x8*)&Kls[krow*128 + pc*8];
      }
#pragma unroll
      for (int qb = 0; qb < 2; ++qb)
#pragma unroll
        for (int nb = 0; nb < 4; ++nb)
          s[qb][nb] = mfma16(kf[nb], q[qb][kk], s[qb][nb]);
    }

    const bool need_mask = (kvt >= 2*qt);
    union PU { uint32_t u[4]; bf16x8 v; };
    PU pb[2][2];   // [qb][kb] PV B-operand fragments

#pragma unroll
    for (int qb = 0; qb < 2; ++qb) {
      if (need_mask) {
        int qpos = qt*128 + wave*32 + qb*16 + l16;
#pragma unroll
        for (int nb = 0; nb < 4; ++nb)
#pragma unroll
          for (int r = 0; r < 4; ++r)
            if (kvt*64 + nb*16 + quad*4 + r > qpos) s[qb][nb][r] = -3e38f;
      }
      float mx = -3e38f;
#pragma unroll
      for (int nb = 0; nb < 4; ++nb)
#pragma unroll
        for (int r = 0; r < 4; ++r) mx = fmaxf(mx, s[qb][nb][r]);
      mx = fmaxf(mx, __shfl_xor(mx, 16, 64));
      mx = fmaxf(mx, __shfl_xor(mx, 32, 64));
      float mnew = fmaxf(m_st[qb], mx);
      float alpha = EXP2F((m_st[qb] - mnew) * CSC);
      m_st[qb] = mnew;
      float mc = mnew * CSC;
      float rs = 0.f;
#pragma unroll
      for (int nb = 0; nb < 4; ++nb)
#pragma unroll
        for (int r = 0; r < 4; ++r) {
          float p = EXP2F(fmaf(s[qb][nb][r], CSC, -mc));
          s[qb][nb][r] = p;
          rs += p;
        }
      rs += __shfl_xor(rs, 16, 64);
      rs += __shfl_xor(rs, 32, 64);
      l_st[qb] = l_st[qb] * alpha + rs;
#pragma unroll
      for (int dhb = 0; dhb < 8; ++dhb) o_acc[dhb][qb] *= alpha;

      // pack P^T to bf16 pairs: pk2[nb][rpair]
      uint32_t pk2[4][2];
#pragma unroll
      for (int nb = 0; nb < 4; ++nb)
#pragma unroll
        for (int rp = 0; rp < 2; ++rp) {
          union BU { bf16x2 v; uint32_t u; } bu;
          bu.v[0] = (bf16_t)s[qb][nb][2*rp];
          bu.v[1] = (bf16_t)s[qb][nb][2*rp+1];
          pk2[nb][rp] = bu.u;
        }
      // cross-quad permutation: C-layout (kv=quad*4+r) -> B-frag (kv=quad*8+j)
      // verified element-wise: dst (quad t,l16), shfl k delivers pair
      // jp = k ^ ((t>>1)<<1) from src lane (2(t&1) + ((k>>1)^(t>>1)))*16+l16,
      // which contributes pk2[2kb + ((srcquad&1)^(k>>1))][k&1].
#pragma unroll
      for (int kb = 0; kb < 2; ++kb)
#pragma unroll
        for (int k = 0; k < 4; ++k) {
          uint32_t x = pk2[2*kb + ((quad & 1) ^ (k >> 1))][k & 1];
          int src = (2*(quad & 1) + ((k >> 1) ^ (quad >> 1))) * 16 + l16;
          uint32_t got = (uint32_t)__shfl((int)x, src, 64);
          pb[qb][kb].u[k ^ ((quad >> 1) << 1)] = got;
        }
    }

    // O^T += V^T P^T : m=dh (8 blocks), n=q (2 blocks), K=kv=64 (2 steps)
#pragma unroll
    for (int dhb = 0; dhb < 8; ++dhb) {
      bf16x8 vf[2];
      int drow = dhb*16 + l16;
#pragma unroll
      for (int kb = 0; kb < 2; ++kb) {
        int pc = (kb*4 + quad) ^ (drow & 7);
        vf[kb] = *(const bf16x8*)&Vls[drow*64 + pc*8];
      }
#pragma unroll
      for (int qb = 0; qb < 2; ++qb)
#pragma unroll
        for (int kb = 0; kb < 2; ++kb)
          o_acc[dhb][qb] = mfma16(vf[kb], pb[qb][kb].v, o_acc[dhb][qb]);
    }
  }

  // epilogue: normalize; store packed bf16 pairs (lane holds dh rows, q col)
#pragma unroll
  for (int qb = 0; qb < 2; ++qb) {
    float inv = 1.f / l_st[qb];
    size_t qrow = (size_t)(b*T_ + qt*128 + wave*32 + qb*16 + l16);
#pragma unroll
    for (int dhb = 0; dhb < 8; ++dhb)
#pragma unroll
      for (int rp = 0; rp < 2; ++rp) {
        union BU { bf16x2 v; uint32_t u; } bu;
        bu.v[0] = (bf16_t)(o_acc[dhb][qb][2*rp]   * inv);
        bu.v[1] = (bf16_t)(o_acc[dhb][qb][2*rp+1] * inv);
        *(uint32_t*)(Ob + qrow*DIM_ + h*DH_ + dhb*16 + quad*4 + 2*rp) = bu.u;
      }
  }
}

// ---------------------------------------------------------------------------
// launch
// ---------------------------------------------------------------------------
extern "C" void kernel_launch(void* const* d_in, const int* in_sizes, int n_in,
                              void* d_out, int out_size, void* d_ws, size_t ws_size,
                              hipStream_t stream) {
  const float* X  = (const float*)d_in[0];
  const float* Wq = (const float*)d_in[1];
  const float* Wk = (const float*)d_in[2];
  const float* Wv = (const float*)d_in[3];
  const float* Wo = (const float*)d_in[4];
  float* out = (float*)d_out;

  // workspace layout (~176.2 MB)
  char* ws = (char*)d_ws;
  const size_t SZ_X    = (size_t)MROWS * DIM_ * 2;   // 33.55 MB
  const size_t SZ_WQKV = (size_t)QS_ * DIM_ * 2;     // 50.33 MB
  const size_t SZ_WO   = (size_t)DIM_ * DIM_ * 2;    // 33.55 MB
  const size_t SZ_QKV  = (size_t)MROWS * QS_ * 2;    // 50.33 MB
  bf16_t* Xb    = (bf16_t*)(ws);                                   // reused as Ob
  bf16_t* WT    = (bf16_t*)(ws + SZ_X);                            // [6144][4096]
  bf16_t* WoT   = (bf16_t*)(ws + SZ_X + SZ_WQKV);
  bf16_t* QKVb  = (bf16_t*)(ws + SZ_X + SZ_WQKV + SZ_WO);          // [4096][6144]
  bf16_t* VT    = (bf16_t*)(ws + SZ_X + SZ_WQKV + SZ_WO + SZ_QKV); // [2][8][128][2048]
  bf16_t* Ob    = Xb;

  // casts / transposes
  {
    int n4 = MROWS * DIM_ / 4;
    cast_f32_bf16<<<(n4 + 255)/256, 256, 0, stream>>>(X, Xb, n4);
  }
  transpose_cast<<<dim3(DIM_/32, DIM_/32), dim3(32,8), 0, stream>>>(Wq, WT, DIM_, DIM_);
  transpose_cast<<<dim3(1024/32, DIM_/32), dim3(32,8), 0, stream>>>(Wk, WT + (size_t)KOFF_*DIM_, DIM_, 1024);
  transpose_cast<<<dim3(1024/32, DIM_/32), dim3(32,8), 0, stream>>>(Wv, WT + (size_t)VOFF_*DIM_, DIM_, 1024);
  transpose_cast<<<dim3(DIM_/32, DIM_/32), dim3(32,8), 0, stream>>>(Wo, WoT, DIM_, DIM_);

  // fused QKV projection: [4096][6144]
  gemm_bt<0><<<dim3(QS_/128, MROWS/128), 256, 0, stream>>>(Xb, WT, QKVb, MROWS, QS_, DIM_);

  // RoPE in place on Q and K columns
  {
    int totq = B_ * T_ * H_ * 64;
    rope_kernel<<<(totq + 255)/256, 256, 0, stream>>>(QKVb, H_, QS_, 0, totq);
    int totk = B_ * T_ * HKV_ * 64;
    rope_kernel<<<(totk + 255)/256, 256, 0, stream>>>(QKVb, HKV_, QS_, KOFF_, totk);
  }

  // V transpose -> VT [b][kv][128][T]
  v_transpose<<<dim3(T_/32, DH_/32, B_*HKV_), dim3(32,8), 0, stream>>>(QKVb + VOFF_, VT);

  // flash attention (flat grid, heavy-first)
  flash_attn<<<dim3(T_/128 * H_ * B_), 256, 0, stream>>>(QKVb, VT, Ob);

  // output projection -> fp32
  gemm_bt<1><<<dim3(DIM_/128, MROWS/128), 256, 0, stream>>>(Ob, WoT, out, MROWS, DIM_, DIM_);
}